// Round 2
// baseline (588.571 us; speedup 1.0000x reference)
//
#include <hip/hip_runtime.h>

// BitNet-style ternary matmul: y = (x @ round(W/mean|W|)^T) * mean|W|
// Pipeline: reduce |W| -> quantize W + cast x to bf16 -> bf16 MFMA GEMM.
//
// GEMM: 256x256 tile, BK=64, 512 threads = 8 waves (2M x 4N), 128 KiB LDS.
// Round-2 schedule: 4 phases per K-tile (one C-quadrant each), fragment reads
// SOFTWARE-PIPELINED one phase ahead into dead register sets, NO blanket
// lgkmcnt(0) before MFMA (compiler emits counted lgkm per use -> LDS service
// overlaps MFMA). ONE barrier per phase. Counted vmcnt(4)/vmcnt(2) per K-tile.
//   p0 (0,0): stage A(j+1)h0 | read B1(j)   | MFMA a0xb0 | lgkm(0) | bar
//   p1 (0,1): stage A(j+1)h1 | read A1(j)   | MFMA a0xb1 | vm(4)   | bar
//   p2 (1,0): stage B(j+2)h0 | MFMA a1xb0 | read B0(j+1) | vm(2)   | bar
//   p3 (1,1): stage B(j+2)h1 | read A0(j+1) | MFMA a1xb1 | lgkm(0) | bar
// W-A-R safety: staged regions' last readers drained by the end-p0/end-p3
// lgkm(0) + barrier chain; R-A-W: vm(4) drains B(j+1) before p2's read,
// vm(2) drains A(j+1) before p3's read (all waves, pre-barrier).

#define K_DIM 4096
#define N_DIM 4096
#define NKT   64   // K_DIM / 64

typedef __bf16 bf16x8 __attribute__((ext_vector_type(8)));
typedef float floatx4 __attribute__((ext_vector_type(4)));

__device__ __forceinline__ unsigned short f32_to_bf16(float f) {
    unsigned int u = __float_as_uint(f);
    u += 0x7fffu + ((u >> 16) & 1u);   // round-to-nearest-even
    return (unsigned short)(u >> 16);
}

// ---------------- kernel 1a: per-block partial sums of |W| ----------------
__global__ void reduce_abs_p1(const float4* __restrict__ W, double* __restrict__ partials, int n4) {
    int tid = blockIdx.x * blockDim.x + threadIdx.x;
    int stride = gridDim.x * blockDim.x;
    float s = 0.f;
    for (int i = tid; i < n4; i += stride) {
        float4 v = W[i];
        s += fabsf(v.x) + fabsf(v.y) + fabsf(v.z) + fabsf(v.w);
    }
    double d = (double)s;
#pragma unroll
    for (int o = 32; o > 0; o >>= 1) d += __shfl_down(d, o, 64);
    __shared__ double lds[4];
    if ((threadIdx.x & 63) == 0) lds[threadIdx.x >> 6] = d;
    __syncthreads();
    if (threadIdx.x == 0)
        partials[blockIdx.x] = lds[0] + lds[1] + lds[2] + lds[3];
}

// ---------------- kernel 1b: final reduce of 1024 partials ----------------
__global__ void reduce_abs_p2(const double* __restrict__ partials, double* __restrict__ out) {
    double d = 0.0;
#pragma unroll
    for (int i = 0; i < 4; ++i) d += partials[threadIdx.x + i * 256];
#pragma unroll
    for (int o = 32; o > 0; o >>= 1) d += __shfl_down(d, o, 64);
    __shared__ double lds[4];
    if ((threadIdx.x & 63) == 0) lds[threadIdx.x >> 6] = d;
    __syncthreads();
    if (threadIdx.x == 0) *out = lds[0] + lds[1] + lds[2] + lds[3];
}

// ---------------- kernel 2: fused W-quantize + x-convert ----------------
__global__ void prep(const float4* __restrict__ W, const float4* __restrict__ X,
                     const double* __restrict__ sum,
                     ushort4* __restrict__ Wq, ushort4* __restrict__ Xb,
                     int nW4, int nX4, double inv_cnt) {
    float scale = (float)(*sum * inv_cnt);
    float d = scale + 1e-5f;
    int tid = blockIdx.x * blockDim.x + threadIdx.x;
    int stride = gridDim.x * blockDim.x;
    for (int i = tid; i < nW4; i += stride) {
        float4 v = W[i];
        ushort4 q;
        q.x = f32_to_bf16(rintf(v.x / d));   // IEEE divide + RNE == numpy round-half-even
        q.y = f32_to_bf16(rintf(v.y / d));
        q.z = f32_to_bf16(rintf(v.z / d));
        q.w = f32_to_bf16(rintf(v.w / d));
        Wq[i] = q;
    }
    for (int i = tid; i < nX4; i += stride) {
        float4 v = X[i];
        ushort4 q;
        q.x = f32_to_bf16(v.x);
        q.y = f32_to_bf16(v.y);
        q.z = f32_to_bf16(v.z);
        q.w = f32_to_bf16(v.w);
        Xb[i] = q;
    }
}

// ---------------- kernel 3: C[m,n] = scale * sum_k A[m,k]*B[n,k] ----------------
__global__ __launch_bounds__(512, 2) void gemm_bt(
    const unsigned short* __restrict__ A, const unsigned short* __restrict__ B,
    float* __restrict__ C, const double* __restrict__ sum, double inv_cnt) {

    // [buf][half][128*64] bf16 = 16 KiB per half; total 128 KiB
    __shared__ __attribute__((aligned(16))) unsigned short As[2][2][128 * 64];
    __shared__ __attribute__((aligned(16))) unsigned short Bs[2][2][128 * 64];

    const int tid  = threadIdx.x;
    const int w    = tid >> 6;     // wave 0..7
    const int lane = tid & 63;
    const int wm   = w >> 2;       // 0..1  -> C rows wm*128..+128
    const int wn   = w & 3;        // 0..3  -> C cols wn*64..+64

    // XCD-aware bijective swizzle: 512 blocks, 8 XCDs, 64 blocks each.
    const int bid = blockIdx.y * gridDim.x + blockIdx.x;
    const int swz = (bid & 7) * 64 + (bid >> 3);
    const size_t m0 = (size_t)(swz >> 4) * 256;
    const size_t n0 = (size_t)(swz & 15) * 256;

    // --- staging addressing -------------------------------------------------
    // One global_load_lds per wave = 64 lanes x 16 B = 8 rows x 128 B (linear
    // LDS dest). lane -> row lane>>3, phys chunk lane&7. LDS image is
    // chunk-swizzled: phys chunk c holds global chunk c ^ (row&7) via
    // pre-swizzled GLOBAL source (dest stays linear, rule #21).
    const int srow   = lane >> 3;
    const int schunk = (lane & 7) ^ srow;
    const unsigned short* pA = A + (m0 + (size_t)(w * 8 + srow)) * K_DIM + schunk * 8;
    const unsigned short* pB = B + (n0 + (size_t)(w * 8 + srow)) * K_DIM + schunk * 8;

    // --- fragment read addressing (16x16x32 MFMA) ---------------------------
    // lane = (fm = lane&15, q = lane>>4); A frag: row = mf*16+fm, k = ks*32+q*8
    // logical chunk = ks*4+q; phys chunk = logical ^ (fm&7)
    const int fm    = lane & 15;
    const int q     = lane >> 4;
    const int cs0   = (q ^ (fm & 7)) * 8;          // ks=0, in shorts
    const int cs1   = ((4 + q) ^ (fm & 7)) * 8;    // ks=1
    const int abase = fm * 64;
    const int bh    = wn >> 1;                      // which B half this wave reads
    const int bbase = (wn & 1) * 4096 + fm * 64;    // row offset within the half

    floatx4 acc[8][4] = {};    // [m-frag][n-frag]
    // pipelined fragment register sets (each read exactly when its old value is dead)
    bf16x8 a0[2][4];   // A rows mh=0 of this K-tile   [ks][t]
    bf16x8 a1[2][4];   // A rows mh=1
    bf16x8 b0v[2][2];  // B cols nh=0                  [ks][u]
    bf16x8 b1v[2][2];  // B cols nh=1

#define STAGE_A(bb, h, kt) do {                                                            \
        __builtin_amdgcn_global_load_lds(                                                  \
            (const __attribute__((address_space(1))) void*)(pA + ((h) * 128 + 0) * K_DIM + (kt) * 64), \
            (__attribute__((address_space(3))) void*)&As[bb][h][w * 512 + 0], 16, 0, 0);   \
        __builtin_amdgcn_global_load_lds(                                                  \
            (const __attribute__((address_space(1))) void*)(pA + ((h) * 128 + 64) * K_DIM + (kt) * 64), \
            (__attribute__((address_space(3))) void*)&As[bb][h][w * 512 + 4096], 16, 0, 0); \
    } while (0)

#define STAGE_B(bb, h, kt) do {                                                            \
        __builtin_amdgcn_global_load_lds(                                                  \
            (const __attribute__((address_space(1))) void*)(pB + ((h) * 128 + 0) * K_DIM + (kt) * 64), \
            (__attribute__((address_space(3))) void*)&Bs[bb][h][w * 512 + 0], 16, 0, 0);   \
        __builtin_amdgcn_global_load_lds(                                                  \
            (const __attribute__((address_space(1))) void*)(pB + ((h) * 128 + 64) * K_DIM + (kt) * 64), \
            (__attribute__((address_space(3))) void*)&Bs[bb][h][w * 512 + 4096], 16, 0, 0); \
    } while (0)

#define READ_A_HALF(dst, b, mh) do {                                                       \
        _Pragma("unroll")                                                                  \
        for (int t = 0; t < 4; ++t) {                                                      \
            dst[0][t] = *(const bf16x8*)&As[b][wm][((mh) * 4 + t) * 1024 + abase + cs0];   \
            dst[1][t] = *(const bf16x8*)&As[b][wm][((mh) * 4 + t) * 1024 + abase + cs1];   \
        }                                                                                  \
    } while (0)

#define READ_B_HALF(dst, b, nh) do {                                                       \
        _Pragma("unroll")                                                                  \
        for (int u = 0; u < 2; ++u) {                                                      \
            dst[0][u] = *(const bf16x8*)&Bs[b][bh][bbase + ((nh) * 2 + u) * 1024 + cs0];   \
            dst[1][u] = *(const bf16x8*)&Bs[b][bh][bbase + ((nh) * 2 + u) * 1024 + cs1];   \
        }                                                                                  \
    } while (0)

#define MFMA16(mh, nh, Af, Bf) do {                                                        \
        _Pragma("unroll")                                                                  \
        for (int t = 0; t < 4; ++t)                                                        \
            _Pragma("unroll")                                                              \
            for (int u = 0; u < 2; ++u) {                                                  \
                acc[(mh) * 4 + t][(nh) * 2 + u] = __builtin_amdgcn_mfma_f32_16x16x32_bf16( \
                    Af[0][t], Bf[0][u], acc[(mh) * 4 + t][(nh) * 2 + u], 0, 0, 0);         \
                acc[(mh) * 4 + t][(nh) * 2 + u] = __builtin_amdgcn_mfma_f32_16x16x32_bf16( \
                    Af[1][t], Bf[1][u], acc[(mh) * 4 + t][(nh) * 2 + u], 0, 0, 0);         \
            }                                                                              \
    } while (0)

    // One K-tile = 4 phases, one barrier each. Reads pipelined one phase ahead.
#define KTILE(b, j, DOA, DOB, PF, VM1S, VM2S) do {                                         \
        /* p0: (0,0) uses a0,b0v; prefetch b1v (dead since p3(j-1)) */                     \
        if (DOA) STAGE_A((b) ^ 1, 0, (j) + 1);                                             \
        READ_B_HALF(b1v, b, 1);                                                            \
        __builtin_amdgcn_s_setprio(1);                                                     \
        MFMA16(0, 0, a0, b0v);                                                             \
        __builtin_amdgcn_s_setprio(0);                                                     \
        asm volatile("s_waitcnt lgkmcnt(0)" ::: "memory");                                 \
        __builtin_amdgcn_s_barrier();                                                      \
        /* p1: (0,1) uses a0,b1v; prefetch a1 (dead since p3(j-1)) */                      \
        if (DOA) STAGE_A((b) ^ 1, 1, (j) + 1);                                             \
        READ_A_HALF(a1, b, 1);                                                             \
        __builtin_amdgcn_s_setprio(1);                                                     \
        MFMA16(0, 1, a0, b1v);                                                             \
        __builtin_amdgcn_s_setprio(0);                                                     \
        asm volatile(VM1S ::: "memory");                                                   \
        __builtin_amdgcn_s_barrier();                                                      \
        /* p2: (1,0) uses a1,b0v; AFTER mfma read b0v <- B0(j+1) (buf^1) */                \
        if (DOB) STAGE_B(b, 0, (j) + 2);                                                   \
        __builtin_amdgcn_s_setprio(1);                                                     \
        MFMA16(1, 0, a1, b0v);                                                             \
        __builtin_amdgcn_s_setprio(0);                                                     \
        if (PF) READ_B_HALF(b0v, (b) ^ 1, 0);                                              \
        asm volatile(VM2S ::: "memory");                                                   \
        __builtin_amdgcn_s_barrier();                                                      \
        /* p3: (1,1) uses a1,b1v; prefetch a0 <- A0(j+1) (dead since p1) */                \
        if (DOB) STAGE_B(b, 1, (j) + 2);                                                   \
        if (PF) READ_A_HALF(a0, (b) ^ 1, 0);                                               \
        __builtin_amdgcn_s_setprio(1);                                                     \
        MFMA16(1, 1, a1, b1v);                                                             \
        __builtin_amdgcn_s_setprio(0);                                                     \
        asm volatile("s_waitcnt lgkmcnt(0)" ::: "memory");                                 \
        __builtin_amdgcn_s_barrier();                                                      \
    } while (0)

    // ---- prologue: kt0 (A+B) -> buf0, B(1) -> buf1; drain kt0, keep B(1) in flight
    STAGE_B(0, 0, 0); STAGE_B(0, 1, 0);
    STAGE_A(0, 0, 0); STAGE_A(0, 1, 0);
    STAGE_B(1, 0, 1); STAGE_B(1, 1, 1);
    asm volatile("s_waitcnt vmcnt(4)" ::: "memory");
    __builtin_amdgcn_s_barrier();
    READ_A_HALF(a0, 0, 0);      // A0(kt0)
    READ_B_HALF(b0v, 0, 0);     // B0(kt0)

    // ---- main loop: 2 K-tiles per iteration, compile-time buffer indices
    for (int j = 0; j < NKT - 2; j += 2) {
        KTILE(0, j,     1, (j < NKT - 2), 1, "s_waitcnt vmcnt(4)", "s_waitcnt vmcnt(2)");
        KTILE(1, j + 1, 1, (j + 1 < NKT - 2), 1, "s_waitcnt vmcnt(4)", "s_waitcnt vmcnt(2)");
    }
    // ---- epilogue K-tiles: kt62 stages A(63) only; kt63 stages nothing
    KTILE(0, NKT - 2, 1, 0, 1, "s_waitcnt vmcnt(4)", "s_waitcnt vmcnt(0)");
    KTILE(1, NKT - 1, 0, 0, 0, "", "");

#undef KTILE
#undef MFMA16
#undef READ_B_HALF
#undef READ_A_HALF
#undef STAGE_B
#undef STAGE_A

    // ---- C write: C/D layout col = lane&15, row = (lane>>4)*4 + reg
    const float scale = (float)(*sum * inv_cnt);
    const size_t m0c = m0 + (size_t)wm * 128;
    const size_t n0c = n0 + (size_t)wn * 64;
#pragma unroll
    for (int mf = 0; mf < 8; ++mf) {
#pragma unroll
        for (int nf = 0; nf < 4; ++nf) {
            float* cp = C + (m0c + mf * 16 + q * 4) * N_DIM + n0c + nf * 16 + fm;
#pragma unroll
            for (int r = 0; r < 4; ++r)
                cp[(size_t)r * N_DIM] = acc[mf][nf][r] * scale;
        }
    }
}

extern "C" void kernel_launch(void* const* d_in, const int* in_sizes, int n_in,
                              void* d_out, int out_size, void* d_ws, size_t ws_size,
                              hipStream_t stream) {
    const float* x = (const float*)d_in[0];
    const float* W = (const float*)d_in[1];
    float* y = (float*)d_out;

    const int nW = in_sizes[1];            // 4096*4096
    const int M  = in_sizes[0] / K_DIM;    // 8192

    double* d_sum = (double*)d_ws;
    double* d_partials = (double*)((char*)d_ws + 16);
    unsigned short* xb = (unsigned short*)((char*)d_ws + 16 + 1024 * sizeof(double));
    unsigned short* wq = xb + (size_t)M * K_DIM;
    const double inv_cnt = 1.0 / (double)nW;

    reduce_abs_p1<<<1024, 256, 0, stream>>>((const float4*)W, d_partials, nW / 4);
    reduce_abs_p2<<<1, 256, 0, stream>>>(d_partials, d_sum);
    prep<<<2048, 256, 0, stream>>>((const float4*)W, (const float4*)x, d_sum,
                                   (ushort4*)wq, (ushort4*)xb,
                                   nW / 4, in_sizes[0] / 4, inv_cnt);

    dim3 grid(N_DIM / 256, M / 256);       // 16 x 32 = 512 blocks
    gemm_bt<<<grid, 512, 0, stream>>>(xb, wq, y, d_sum, inv_cnt);
}

// Round 3
// 578.580 us; speedup vs baseline: 1.0173x; 1.0173x over previous
//
#include <hip/hip_runtime.h>

// BitNet-style ternary matmul: y = (x @ round(W/mean|W|)^T) * mean|W|
// Pipeline: reduce |W| -> (quantize W + cast x to bf16, fused final reduce) -> bf16 MFMA GEMM.
//
// GEMM: 256x256 tile, BK=64, 512 threads = 8 waves (2M x 4N), 128 KiB LDS.
// Round-3 schedule: 4 phases per K-tile, quadrant order (0,0),(0,1),(1,1),(1,0),
// fragment reads ONE PHASE AHEAD of consumption (per-phase ds_read counts
// 4/8/4/8 -- matching m201's "4 or 8" signature), TWO barriers per phase
// (round-2's 1-barrier drift regressed), NO blanket lgkmcnt(0) (compiler
// inserts counted lgkm for the cross-phase read->MFMA dep).
//   p0: read b1(j)->Q [4]   | stage A(j+1)h0 | bar | MFMA (0,0) a0*P | bar
//   p1: read a1(j)   [8]    | stage A(j+1)h1 | bar | MFMA (0,1) a0*Q | vm(4) | bar
//   p2: stage B(j+2)h0      | bar | MFMA (1,1) a1*Q | read B0(j+1)->Q [4] | vm(2) | bar
//   p3: read A0(j+1)->a0 [8]| stage B(j+2)h1 | bar | MFMA (1,0) a1*P | bar
// B register slots parity-swap per tile (P<->Q); A slots fixed (a0 dead after
// p1, a1 dead after p3). vmcnt ledger (2 loads per staged half-tile):
//   p1-end: outstanding B(j+1)[4]+A(j+1)[4] -> vm(4) drains B(j+1) (read p2)
//   p2-end: outstanding A(j+1)[4]+B(j+2)h0[2] -> vm(2) drains A(j+1) (read p3)
// Never vmcnt(0) in steady state. W-A-R: every staged region's last ds_read
// is >=2 barriers upstream and was lgkm-drained before its consuming MFMA.

#define K_DIM 4096
#define N_DIM 4096
#define NKT   64   // K_DIM / 64

typedef __bf16 bf16x8 __attribute__((ext_vector_type(8)));
typedef float floatx4 __attribute__((ext_vector_type(4)));

__device__ __forceinline__ unsigned short f32_to_bf16(float f) {
    unsigned int u = __float_as_uint(f);
    u += 0x7fffu + ((u >> 16) & 1u);   // round-to-nearest-even
    return (unsigned short)(u >> 16);
}

// ---------------- kernel 1: per-block partial sums of |W| ----------------
__global__ void reduce_abs_p1(const float4* __restrict__ W, double* __restrict__ partials, int n4) {
    int tid = blockIdx.x * blockDim.x + threadIdx.x;
    int stride = gridDim.x * blockDim.x;
    float s = 0.f;
    for (int i = tid; i < n4; i += stride) {
        float4 v = W[i];
        s += fabsf(v.x) + fabsf(v.y) + fabsf(v.z) + fabsf(v.w);
    }
    double d = (double)s;
#pragma unroll
    for (int o = 32; o > 0; o >>= 1) d += __shfl_down(d, o, 64);
    __shared__ double lds[4];
    if ((threadIdx.x & 63) == 0) lds[threadIdx.x >> 6] = d;
    __syncthreads();
    if (threadIdx.x == 0)
        partials[blockIdx.x] = lds[0] + lds[1] + lds[2] + lds[3];
}

// ---------------- kernel 2: fused final-reduce + W-quantize + x-convert ----------------
// Each block re-reduces the 1024 partials (L2-hot, ~8 KB) itself; block 0
// publishes d_sum for the GEMM epilogue. Saves the reduce_p2 launch.
__global__ void prep(const float4* __restrict__ W, const float4* __restrict__ X,
                     const double* __restrict__ partials, double* __restrict__ sum_out,
                     ushort4* __restrict__ Wq, ushort4* __restrict__ Xb,
                     int nW4, int nX4, double inv_cnt) {
    __shared__ double lds[4];
    double dsum;
    {
        int t = threadIdx.x;
        double d = partials[t] + partials[t + 256] + partials[t + 512] + partials[t + 768];
#pragma unroll
        for (int o = 32; o > 0; o >>= 1) d += __shfl_down(d, o, 64);
        if ((t & 63) == 0) lds[t >> 6] = d;
        __syncthreads();
        dsum = lds[0] + lds[1] + lds[2] + lds[3];
        if (blockIdx.x == 0 && t == 0) *sum_out = dsum;
    }
    float scale = (float)(dsum * inv_cnt);
    float d = scale + 1e-5f;
    int tid = blockIdx.x * blockDim.x + threadIdx.x;
    int stride = gridDim.x * blockDim.x;
    for (int i = tid; i < nW4; i += stride) {
        float4 v = W[i];
        ushort4 q;
        q.x = f32_to_bf16(rintf(v.x / d));   // IEEE divide + RNE == numpy round-half-even
        q.y = f32_to_bf16(rintf(v.y / d));
        q.z = f32_to_bf16(rintf(v.z / d));
        q.w = f32_to_bf16(rintf(v.w / d));
        Wq[i] = q;
    }
    for (int i = tid; i < nX4; i += stride) {
        float4 v = X[i];
        ushort4 q;
        q.x = f32_to_bf16(v.x);
        q.y = f32_to_bf16(v.y);
        q.z = f32_to_bf16(v.z);
        q.w = f32_to_bf16(v.w);
        Xb[i] = q;
    }
}

// ---------------- kernel 3: C[m,n] = scale * sum_k A[m,k]*B[n,k] ----------------
__global__ __launch_bounds__(512, 2) void gemm_bt(
    const unsigned short* __restrict__ A, const unsigned short* __restrict__ B,
    float* __restrict__ C, const double* __restrict__ sum, double inv_cnt) {

    // [buf][half][128*64] bf16 = 16 KiB per half; total 128 KiB
    __shared__ __attribute__((aligned(16))) unsigned short As[2][2][128 * 64];
    __shared__ __attribute__((aligned(16))) unsigned short Bs[2][2][128 * 64];

    const int tid  = threadIdx.x;
    const int w    = tid >> 6;     // wave 0..7
    const int lane = tid & 63;
    const int wm   = w >> 2;       // 0..1  -> C rows wm*128..+128
    const int wn   = w & 3;        // 0..3  -> C cols wn*64..+64

    // XCD-aware bijective swizzle: 512 blocks, 8 XCDs, 64 blocks each.
    const int bid = blockIdx.y * gridDim.x + blockIdx.x;
    const int swz = (bid & 7) * 64 + (bid >> 3);
    const size_t m0 = (size_t)(swz >> 4) * 256;
    const size_t n0 = (size_t)(swz & 15) * 256;

    // --- staging addressing: linear LDS dest + pre-swizzled global source ----
    const int srow   = lane >> 3;
    const int schunk = (lane & 7) ^ srow;
    const unsigned short* pA = A + (m0 + (size_t)(w * 8 + srow)) * K_DIM + schunk * 8;
    const unsigned short* pB = B + (n0 + (size_t)(w * 8 + srow)) * K_DIM + schunk * 8;

    // --- fragment read addressing (16x16x32 MFMA) ---------------------------
    const int fm    = lane & 15;
    const int q     = lane >> 4;
    const int cs0   = (q ^ (fm & 7)) * 8;          // ks=0, in shorts
    const int cs1   = ((4 + q) ^ (fm & 7)) * 8;    // ks=1
    const int abase = fm * 64;
    const int bh    = wn >> 1;                      // which B half this wave reads
    const int bbase = (wn & 1) * 4096 + fm * 64;    // row offset within the half

    floatx4 acc[8][4] = {};    // [m-frag][n-frag]
    // pipelined fragment sets: a0/a1 fixed roles; Be/Bo parity-swap per tile
    bf16x8 a0[2][4];   // A half mh=0 of current tile   [ks][t]
    bf16x8 a1[2][4];   // A half mh=1
    bf16x8 Be[2][2];   // B sets                        [ks][u]
    bf16x8 Bo[2][2];

#define STAGE_A(bb, h, kt) do {                                                            \
        __builtin_amdgcn_global_load_lds(                                                  \
            (const __attribute__((address_space(1))) void*)(pA + ((h) * 128 + 0) * K_DIM + (kt) * 64), \
            (__attribute__((address_space(3))) void*)&As[bb][h][w * 512 + 0], 16, 0, 0);   \
        __builtin_amdgcn_global_load_lds(                                                  \
            (const __attribute__((address_space(1))) void*)(pA + ((h) * 128 + 64) * K_DIM + (kt) * 64), \
            (__attribute__((address_space(3))) void*)&As[bb][h][w * 512 + 4096], 16, 0, 0); \
    } while (0)

#define STAGE_B(bb, h, kt) do {                                                            \
        __builtin_amdgcn_global_load_lds(                                                  \
            (const __attribute__((address_space(1))) void*)(pB + ((h) * 128 + 0) * K_DIM + (kt) * 64), \
            (__attribute__((address_space(3))) void*)&Bs[bb][h][w * 512 + 0], 16, 0, 0);   \
        __builtin_amdgcn_global_load_lds(                                                  \
            (const __attribute__((address_space(1))) void*)(pB + ((h) * 128 + 64) * K_DIM + (kt) * 64), \
            (__attribute__((address_space(3))) void*)&Bs[bb][h][w * 512 + 4096], 16, 0, 0); \
    } while (0)

#define READ_A_HALF(dst, b, mh) do {                                                       \
        _Pragma("unroll")                                                                  \
        for (int t = 0; t < 4; ++t) {                                                      \
            dst[0][t] = *(const bf16x8*)&As[b][wm][((mh) * 4 + t) * 1024 + abase + cs0];   \
            dst[1][t] = *(const bf16x8*)&As[b][wm][((mh) * 4 + t) * 1024 + abase + cs1];   \
        }                                                                                  \
    } while (0)

#define READ_B_HALF(dst, b, nh) do {                                                       \
        _Pragma("unroll")                                                                  \
        for (int u = 0; u < 2; ++u) {                                                      \
            dst[0][u] = *(const bf16x8*)&Bs[b][bh][bbase + ((nh) * 2 + u) * 1024 + cs0];   \
            dst[1][u] = *(const bf16x8*)&Bs[b][bh][bbase + ((nh) * 2 + u) * 1024 + cs1];   \
        }                                                                                  \
    } while (0)

    // ks-outer: 8 independent accs between the two dependent ks-steps
#define MFMA16(mh, nh, Af, Bf) do {                                                        \
        _Pragma("unroll")                                                                  \
        for (int ks = 0; ks < 2; ++ks)                                                     \
            _Pragma("unroll")                                                              \
            for (int t = 0; t < 4; ++t)                                                    \
                _Pragma("unroll")                                                          \
                for (int u = 0; u < 2; ++u)                                                \
                    acc[(mh) * 4 + t][(nh) * 2 + u] = __builtin_amdgcn_mfma_f32_16x16x32_bf16( \
                        Af[ks][t], Bf[ks][u], acc[(mh) * 4 + t][(nh) * 2 + u], 0, 0, 0);   \
    } while (0)

    // One K-tile = 4 phases; reads one phase ahead; 2 barriers/phase.
#define KTILE(b, j, P, Q, DOA, DOB, PFB, PFA, VM1S, VM2S) do {                             \
        /* p0: MFMA (0,0) a0*P ; read b1(j)->Q ; stage A(j+1)h0 */                         \
        READ_B_HALF(Q, b, 1);                                                              \
        if (DOA) STAGE_A((b) ^ 1, 0, (j) + 1);                                             \
        __builtin_amdgcn_s_barrier();                                                      \
        __builtin_amdgcn_s_setprio(1);                                                     \
        MFMA16(0, 0, a0, P);                                                               \
        __builtin_amdgcn_s_setprio(0);                                                     \
        __builtin_amdgcn_s_barrier();                                                      \
        /* p1: MFMA (0,1) a0*Q ; read a1(j) ; stage A(j+1)h1 */                            \
        READ_A_HALF(a1, b, 1);                                                             \
        if (DOA) STAGE_A((b) ^ 1, 1, (j) + 1);                                             \
        __builtin_amdgcn_s_barrier();                                                      \
        __builtin_amdgcn_s_setprio(1);                                                     \
        MFMA16(0, 1, a0, Q);                                                               \
        __builtin_amdgcn_s_setprio(0);                                                     \
        asm volatile(VM1S ::: "memory");                                                   \
        __builtin_amdgcn_s_barrier();                                                      \
        /* p2: MFMA (1,1) a1*Q ; then read B0(j+1)->Q ; stage B(j+2)h0 */                  \
        if (DOB) STAGE_B(b, 0, (j) + 2);                                                   \
        __builtin_amdgcn_s_barrier();                                                      \
        __builtin_amdgcn_s_setprio(1);                                                     \
        MFMA16(1, 1, a1, Q);                                                               \
        __builtin_amdgcn_s_setprio(0);                                                     \
        if (PFB) READ_B_HALF(Q, (b) ^ 1, 0);                                               \
        asm volatile(VM2S ::: "memory");                                                   \
        __builtin_amdgcn_s_barrier();                                                      \
        /* p3: MFMA (1,0) a1*P ; read A0(j+1)->a0 ; stage B(j+2)h1 */                      \
        if (PFA) READ_A_HALF(a0, (b) ^ 1, 0);                                              \
        if (DOB) STAGE_B(b, 1, (j) + 2);                                                   \
        __builtin_amdgcn_s_barrier();                                                      \
        __builtin_amdgcn_s_setprio(1);                                                     \
        MFMA16(1, 0, a1, P);                                                               \
        __builtin_amdgcn_s_setprio(0);                                                     \
        __builtin_amdgcn_s_barrier();                                                      \
    } while (0)

    // ---- prologue: A(0),B(0) -> buf0, B(1) -> buf1; drain kt0, keep B(1) in flight
    STAGE_A(0, 0, 0); STAGE_A(0, 1, 0);
    STAGE_B(0, 0, 0); STAGE_B(0, 1, 0);
    STAGE_B(1, 0, 1); STAGE_B(1, 1, 1);
    asm volatile("s_waitcnt vmcnt(4)" ::: "memory");   // A(0),B(0) landed; B(1) in flight
    __builtin_amdgcn_s_barrier();
    READ_A_HALF(a0, 0, 0);      // A0(kt0)
    READ_B_HALF(Be, 0, 0);      // B0(kt0) -> P of tile 0

    // ---- main loop: 2 K-tiles per iteration (B-set parity swap is compile-time)
    for (int j = 0; j < NKT - 2; j += 2) {
        KTILE(0, j,     Be, Bo, 1, 1, 1, 1, "s_waitcnt vmcnt(4)", "s_waitcnt vmcnt(2)");
        KTILE(1, j + 1, Bo, Be, 1, 1, 1, 1, "s_waitcnt vmcnt(4)", "s_waitcnt vmcnt(2)");
    }
    // ---- epilogue: tile 62 stages A(63) only, drains fully at p2-end; tile 63 bare
    KTILE(0, NKT - 2, Be, Bo, 1, 0, 1, 1, "s_waitcnt vmcnt(4)", "s_waitcnt vmcnt(0)");
    KTILE(1, NKT - 1, Bo, Be, 0, 0, 0, 0, "", "");

#undef KTILE
#undef MFMA16
#undef READ_B_HALF
#undef READ_A_HALF
#undef STAGE_B
#undef STAGE_A

    // ---- C write: C/D layout col = lane&15, row = (lane>>4)*4 + reg
    const float scale = (float)(*sum * inv_cnt);
    const size_t m0c = m0 + (size_t)wm * 128;
    const size_t n0c = n0 + (size_t)wn * 64;
#pragma unroll
    for (int mf = 0; mf < 8; ++mf) {
#pragma unroll
        for (int nf = 0; nf < 4; ++nf) {
            float* cp = C + (m0c + mf * 16 + q * 4) * N_DIM + n0c + nf * 16 + fm;
#pragma unroll
            for (int r = 0; r < 4; ++r)
                cp[(size_t)r * N_DIM] = acc[mf][nf][r] * scale;
        }
    }
}

extern "C" void kernel_launch(void* const* d_in, const int* in_sizes, int n_in,
                              void* d_out, int out_size, void* d_ws, size_t ws_size,
                              hipStream_t stream) {
    const float* x = (const float*)d_in[0];
    const float* W = (const float*)d_in[1];
    float* y = (float*)d_out;

    const int nW = in_sizes[1];            // 4096*4096
    const int M  = in_sizes[0] / K_DIM;    // 8192

    double* d_sum = (double*)d_ws;
    double* d_partials = (double*)((char*)d_ws + 16);
    unsigned short* xb = (unsigned short*)((char*)d_ws + 16 + 1024 * sizeof(double));
    unsigned short* wq = xb + (size_t)M * K_DIM;
    const double inv_cnt = 1.0 / (double)nW;

    reduce_abs_p1<<<1024, 256, 0, stream>>>((const float4*)W, d_partials, nW / 4);
    prep<<<2048, 256, 0, stream>>>((const float4*)W, (const float4*)x, d_partials, d_sum,
                                   (ushort4*)wq, (ushort4*)xb,
                                   nW / 4, in_sizes[0] / 4, inv_cnt);

    dim3 grid(N_DIM / 256, M / 256);       // 16 x 32 = 512 blocks
    gemm_bt<<<grid, 512, 0, stream>>>(xb, wq, y, d_sum, inv_cnt);
}

// Round 6
// 575.232 us; speedup vs baseline: 1.0232x; 1.0058x over previous
//
#include <hip/hip_runtime.h>

// BitNet-style ternary matmul: y = (x @ round(W/mean|W|)^T) * mean|W|
// Pipeline: reduce |W| -> (fused final reduce + quantize W + cast x) -> bf16 MFMA GEMM.
//
// GEMM: 256x256 tile, BK=64, 512 threads = 8 waves (2M x 4N), 128 KiB LDS.
// Round-4 kernel (resubmitted: rounds 4 & 5 hit GPU acquisition timeouts --
// still unmeasured). ROUND-1 SKELETON (best measured: 307 us / 38.5% MfmaUtil)
// with the MFMA shape swapped 16x16x32 -> 32x32x16 (2382 vs 2075 TF ubench
// ceiling, half the instruction count, same LDS bytes, same register shape).
// Phases per K-tile (reads 12/4/8/0, one vm(4) per tile, 2 barriers/phase):
//   p0: read A0(8)+B0(4) | stage A(j+1)h0 | lgkm(8) | bar | lgkm(0) | MFMA(0,0) | bar
//   p1: read B1(4)       | stage A(j+1)h1 |           bar | lgkm(0) | MFMA(0,1) | bar
//   p2: read A1(8)       | stage B(j+2)h0 |           bar | lgkm(0) | MFMA(1,0) | bar
//   p3:                  | stage B(j+2)h1 |           bar |           MFMA(1,1) | vm(4) | bar
// vm ledger: enter j with B(j+1)=4 outstanding; p0..p3 add 2 each -> 12;
// vm(4) drains B(j+1)+A(j+1) (issued 4-7 phases prior), leaves B(j+2)=4.

#define K_DIM 4096
#define N_DIM 4096
#define NKT   64   // K_DIM / 64

typedef __bf16 bf16x8 __attribute__((ext_vector_type(8)));
typedef float floatx16 __attribute__((ext_vector_type(16)));

__device__ __forceinline__ unsigned short f32_to_bf16(float f) {
    unsigned int u = __float_as_uint(f);
    u += 0x7fffu + ((u >> 16) & 1u);   // round-to-nearest-even
    return (unsigned short)(u >> 16);
}

// ---------------- kernel 1: per-block partial sums of |W| ----------------
__global__ void reduce_abs_p1(const float4* __restrict__ W, double* __restrict__ partials, int n4) {
    int tid = blockIdx.x * blockDim.x + threadIdx.x;
    int stride = gridDim.x * blockDim.x;
    float s = 0.f;
    for (int i = tid; i < n4; i += stride) {
        float4 v = W[i];
        s += fabsf(v.x) + fabsf(v.y) + fabsf(v.z) + fabsf(v.w);
    }
    double d = (double)s;
#pragma unroll
    for (int o = 32; o > 0; o >>= 1) d += __shfl_down(d, o, 64);
    __shared__ double lds[4];
    if ((threadIdx.x & 63) == 0) lds[threadIdx.x >> 6] = d;
    __syncthreads();
    if (threadIdx.x == 0)
        partials[blockIdx.x] = lds[0] + lds[1] + lds[2] + lds[3];
}

// ---------------- kernel 2: fused final-reduce + W-quantize + x-convert ----------------
__global__ void prep(const float4* __restrict__ W, const float4* __restrict__ X,
                     const double* __restrict__ partials, double* __restrict__ sum_out,
                     ushort4* __restrict__ Wq, ushort4* __restrict__ Xb,
                     int nW4, int nX4, double inv_cnt) {
    __shared__ double lds[4];
    double dsum;
    {
        int t = threadIdx.x;
        double d = partials[t] + partials[t + 256] + partials[t + 512] + partials[t + 768];
#pragma unroll
        for (int o = 32; o > 0; o >>= 1) d += __shfl_down(d, o, 64);
        if ((t & 63) == 0) lds[t >> 6] = d;
        __syncthreads();
        dsum = lds[0] + lds[1] + lds[2] + lds[3];
        if (blockIdx.x == 0 && t == 0) *sum_out = dsum;
    }
    float scale = (float)(dsum * inv_cnt);
    float d = scale + 1e-5f;
    int tid = blockIdx.x * blockDim.x + threadIdx.x;
    int stride = gridDim.x * blockDim.x;
    for (int i = tid; i < nW4; i += stride) {
        float4 v = W[i];
        ushort4 q;
        q.x = f32_to_bf16(rintf(v.x / d));   // IEEE divide + RNE == numpy round-half-even
        q.y = f32_to_bf16(rintf(v.y / d));
        q.z = f32_to_bf16(rintf(v.z / d));
        q.w = f32_to_bf16(rintf(v.w / d));
        Wq[i] = q;
    }
    for (int i = tid; i < nX4; i += stride) {
        float4 v = X[i];
        ushort4 q;
        q.x = f32_to_bf16(v.x);
        q.y = f32_to_bf16(v.y);
        q.z = f32_to_bf16(v.z);
        q.w = f32_to_bf16(v.w);
        Xb[i] = q;
    }
}

// ---------------- kernel 3: C[m,n] = scale * sum_k A[m,k]*B[n,k] ----------------
__global__ __launch_bounds__(512, 2) void gemm_bt(
    const unsigned short* __restrict__ A, const unsigned short* __restrict__ B,
    float* __restrict__ C, const double* __restrict__ sum, double inv_cnt) {

    // [buf][half][128*64] bf16 = 16 KiB per half; total 128 KiB
    __shared__ __attribute__((aligned(16))) unsigned short As[2][2][128 * 64];
    __shared__ __attribute__((aligned(16))) unsigned short Bs[2][2][128 * 64];

    const int tid  = threadIdx.x;
    const int w    = tid >> 6;     // wave 0..7
    const int lane = tid & 63;
    const int wm   = w >> 2;       // 0..1  -> C rows wm*128..+128
    const int wn   = w & 3;        // 0..3  -> C cols wn*64..+64

    // XCD-aware bijective swizzle: 512 blocks, 8 XCDs, 64 blocks each.
    const int bid = blockIdx.y * gridDim.x + blockIdx.x;
    const int swz = (bid & 7) * 64 + (bid >> 3);
    const size_t m0 = (size_t)(swz >> 4) * 256;
    const size_t n0 = (size_t)(swz & 15) * 256;

    // --- staging addressing: linear LDS dest + pre-swizzled global source ----
    // phys chunk p of row r holds global 16B-chunk p ^ (r&7)  (rule #21 pair)
    const int srow   = lane >> 3;
    const int schunk = (lane & 7) ^ srow;
    const unsigned short* pA = A + (m0 + (size_t)(w * 8 + srow)) * K_DIM + schunk * 8;
    const unsigned short* pB = B + (n0 + (size_t)(w * 8 + srow)) * K_DIM + schunk * 8;

    // --- fragment read addressing (32x32x16 MFMA) ---------------------------
    // lane = (r31 = lane&31, hk = lane>>5); A frag (mf, ks):
    //   row = mf*32 + r31, k-16B-chunk logical = ks*2 + hk, phys = logical ^ (r31&7)
    const int r31   = lane & 31;
    const int hk    = lane >> 5;
    const int xor7  = r31 & 7;
    const int abase = r31 * 64;                       // shorts
    const int bh    = wn >> 1;                        // which B half this wave reads
    const int bbase = ((wn & 1) * 64 + r31) * 64;     // shorts, within the half

#define CHK(ks) ((((ks) * 2 + hk) ^ xor7) * 8)

    floatx16 acc[4][2] = {};   // [mf][nf], 128 regs
    bf16x8 a0f[2][4];          // A half mh=0: [mfl][ks]
    bf16x8 a1f[2][4];          // A half mh=1
    bf16x8 b0f[4];             // B nf=0: [ks]
    bf16x8 b1f[4];             // B nf=1

#define STAGE_A(bb, h, kt) do {                                                            \
        __builtin_amdgcn_global_load_lds(                                                  \
            (const __attribute__((address_space(1))) void*)(pA + ((h) * 128 + 0) * K_DIM + (kt) * 64), \
            (__attribute__((address_space(3))) void*)&As[bb][h][w * 512 + 0], 16, 0, 0);   \
        __builtin_amdgcn_global_load_lds(                                                  \
            (const __attribute__((address_space(1))) void*)(pA + ((h) * 128 + 64) * K_DIM + (kt) * 64), \
            (__attribute__((address_space(3))) void*)&As[bb][h][w * 512 + 4096], 16, 0, 0); \
    } while (0)

#define STAGE_B(bb, h, kt) do {                                                            \
        __builtin_amdgcn_global_load_lds(                                                  \
            (const __attribute__((address_space(1))) void*)(pB + ((h) * 128 + 0) * K_DIM + (kt) * 64), \
            (__attribute__((address_space(3))) void*)&Bs[bb][h][w * 512 + 0], 16, 0, 0);   \
        __builtin_amdgcn_global_load_lds(                                                  \
            (const __attribute__((address_space(1))) void*)(pB + ((h) * 128 + 64) * K_DIM + (kt) * 64), \
            (__attribute__((address_space(3))) void*)&Bs[bb][h][w * 512 + 4096], 16, 0, 0); \
    } while (0)

#define READ_A_HALF(dst, b, mh) do {                                                       \
        _Pragma("unroll")                                                                  \
        for (int mfl = 0; mfl < 2; ++mfl)                                                  \
            _Pragma("unroll")                                                              \
            for (int ks = 0; ks < 4; ++ks)                                                 \
                dst[mfl][ks] = *(const bf16x8*)                                            \
                    &As[b][wm][((mh) * 2 + mfl) * 2048 + abase + CHK(ks)];                 \
    } while (0)

#define READ_B_NF(dst, b, nf) do {                                                         \
        _Pragma("unroll")                                                                  \
        for (int ks = 0; ks < 4; ++ks)                                                     \
            dst[ks] = *(const bf16x8*)                                                     \
                &Bs[b][bh][bbase + (nf) * 2048 + CHK(ks)];                                 \
    } while (0)

    // one C-quadrant x K=64: 2 mfl x 4 ks = 8 x mfma_32x32x16 (2 indep per ks)
#define MFMA8(mh, nf, Af, Bf) do {                                                         \
        _Pragma("unroll")                                                                  \
        for (int ks = 0; ks < 4; ++ks)                                                     \
            _Pragma("unroll")                                                              \
            for (int mfl = 0; mfl < 2; ++mfl)                                              \
                acc[(mh) * 2 + mfl][nf] = __builtin_amdgcn_mfma_f32_32x32x16_bf16(         \
                    Af[mfl][ks], Bf[ks], acc[(mh) * 2 + mfl][nf], 0, 0, 0);                \
    } while (0)

#define KTILE(b, j, DOA, DOB, VMW) do {                                                    \
        /* p0 */                                                                           \
        READ_A_HALF(a0f, b, 0);                                                            \
        READ_B_NF(b0f, b, 0);                                                              \
        if (DOA) STAGE_A((b) ^ 1, 0, (j) + 1);                                             \
        asm volatile("s_waitcnt lgkmcnt(8)" ::: "memory");                                 \
        __builtin_amdgcn_s_barrier();                                                      \
        asm volatile("s_waitcnt lgkmcnt(0)" ::: "memory");                                 \
        __builtin_amdgcn_s_setprio(1);                                                     \
        MFMA8(0, 0, a0f, b0f);                                                             \
        __builtin_amdgcn_s_setprio(0);                                                     \
        __builtin_amdgcn_s_barrier();                                                      \
        /* p1 */                                                                           \
        READ_B_NF(b1f, b, 1);                                                              \
        if (DOA) STAGE_A((b) ^ 1, 1, (j) + 1);                                             \
        __builtin_amdgcn_s_barrier();                                                      \
        asm volatile("s_waitcnt lgkmcnt(0)" ::: "memory");                                 \
        __builtin_amdgcn_s_setprio(1);                                                     \
        MFMA8(0, 1, a0f, b1f);                                                             \
        __builtin_amdgcn_s_setprio(0);                                                     \
        __builtin_amdgcn_s_barrier();                                                      \
        /* p2 */                                                                           \
        READ_A_HALF(a1f, b, 1);                                                            \
        if (DOB) STAGE_B(b, 0, (j) + 2);                                                   \
        __builtin_amdgcn_s_barrier();                                                      \
        asm volatile("s_waitcnt lgkmcnt(0)" ::: "memory");                                 \
        __builtin_amdgcn_s_setprio(1);                                                     \
        MFMA8(1, 0, a1f, b0f);                                                             \
        __builtin_amdgcn_s_setprio(0);                                                     \
        __builtin_amdgcn_s_barrier();                                                      \
        /* p3 */                                                                           \
        if (DOB) STAGE_B(b, 1, (j) + 2);                                                   \
        __builtin_amdgcn_s_barrier();                                                      \
        __builtin_amdgcn_s_setprio(1);                                                     \
        MFMA8(1, 1, a1f, b1f);                                                             \
        __builtin_amdgcn_s_setprio(0);                                                     \
        asm volatile(VMW ::: "memory");                                                    \
        __builtin_amdgcn_s_barrier();                                                      \
    } while (0)

    // ---- prologue: kt0 (A+B) -> buf0, B(1) -> buf1; drain kt0, keep B(1) in flight
    STAGE_B(0, 0, 0); STAGE_B(0, 1, 0);
    STAGE_A(0, 0, 0); STAGE_A(0, 1, 0);
    STAGE_B(1, 0, 1); STAGE_B(1, 1, 1);
    asm volatile("s_waitcnt vmcnt(4)" ::: "memory");
    __builtin_amdgcn_s_barrier();

    // ---- main loop: 2 K-tiles per iteration, compile-time buffer indices
    for (int j = 0; j < NKT - 2; j += 2) {
        KTILE(0, j,     1, 1, "s_waitcnt vmcnt(4)");
        KTILE(1, j + 1, 1, 1, "s_waitcnt vmcnt(4)");
    }
    // ---- epilogue: kt62 stages A(63), drains fully; kt63 stages nothing
    KTILE(0, NKT - 2, 1, 0, "s_waitcnt vmcnt(0)");
    KTILE(1, NKT - 1, 0, 0, "");

#undef KTILE
#undef MFMA8
#undef READ_B_NF
#undef READ_A_HALF
#undef STAGE_B
#undef STAGE_A
#undef CHK

    // ---- C write: 32x32 C/D layout col = lane&31, row = (reg&3)+8*(reg>>2)+4*hk
    const float scale = (float)(*sum * inv_cnt);
    const size_t m0c = m0 + (size_t)wm * 128;
    const size_t n0c = n0 + (size_t)wn * 64;
#pragma unroll
    for (int mf = 0; mf < 4; ++mf) {
#pragma unroll
        for (int nf = 0; nf < 2; ++nf) {
#pragma unroll
            for (int r = 0; r < 16; ++r) {
                size_t row = m0c + mf * 32 + (r & 3) + 8 * (r >> 2) + 4 * hk;
                size_t col = n0c + nf * 32 + r31;
                C[row * N_DIM + col] = acc[mf][nf][r] * scale;
            }
        }
    }
}

extern "C" void kernel_launch(void* const* d_in, const int* in_sizes, int n_in,
                              void* d_out, int out_size, void* d_ws, size_t ws_size,
                              hipStream_t stream) {
    const float* x = (const float*)d_in[0];
    const float* W = (const float*)d_in[1];
    float* y = (float*)d_out;

    const int nW = in_sizes[1];            // 4096*4096
    const int M  = in_sizes[0] / K_DIM;    // 8192

    double* d_sum = (double*)d_ws;
    double* d_partials = (double*)((char*)d_ws + 16);
    unsigned short* xb = (unsigned short*)((char*)d_ws + 16 + 1024 * sizeof(double));
    unsigned short* wq = xb + (size_t)M * K_DIM;
    const double inv_cnt = 1.0 / (double)nW;

    reduce_abs_p1<<<1024, 256, 0, stream>>>((const float4*)W, d_partials, nW / 4);
    prep<<<2048, 256, 0, stream>>>((const float4*)W, (const float4*)x, d_partials, d_sum,
                                   (ushort4*)wq, (ushort4*)xb,
                                   nW / 4, in_sizes[0] / 4, inv_cnt);

    dim3 grid(N_DIM / 256, M / 256);       // 16 x 32 = 512 blocks
    gemm_bt<<<grid, 512, 0, stream>>>(xb, wq, y, d_sum, inv_cnt);
}

// Round 8
// 570.946 us; speedup vs baseline: 1.0309x; 1.0075x over previous
//
#include <hip/hip_runtime.h>

// BitNet-style ternary matmul: y = (x @ round(W/mean|W|)^T) * mean|W|
// Round-7 kernel, resubmitted after GPU acquisition timeout (unmeasured):
// (a) GEMM byte-exact round-1 best (307 us, 38.5% MfmaUtil, 0 bank conflicts);
//     the 32x32x16 variant measured neutral-to-worse (2.5e7 conflicts) -> reverted.
// (b) Front-end rebalanced to isolate the ~250 us of non-GEMM time:
//     k1 = x->bf16 cast + |W| partial reduce (one pass over each input),
//     k2 = final reduce (2048 partials) + W quantize (W L3-resident after k1).

#define K_DIM 4096
#define N_DIM 4096
#define NKT   64   // K_DIM / 64

typedef __bf16 bf16x8 __attribute__((ext_vector_type(8)));
typedef float floatx4 __attribute__((ext_vector_type(4)));

__device__ __forceinline__ unsigned short f32_to_bf16(float f) {
    unsigned int u = __float_as_uint(f);
    u += 0x7fffu + ((u >> 16) & 1u);   // round-to-nearest-even
    return (unsigned short)(u >> 16);
}

// ---------------- kernel 1: x -> bf16 cast  +  per-block partial sums of |W| ----
__global__ void k1_cast_reduce(const float4* __restrict__ X, ushort4* __restrict__ Xb,
                               const float4* __restrict__ W, double* __restrict__ partials,
                               int nX4, int nW4) {
    int tid = blockIdx.x * blockDim.x + threadIdx.x;
    int stride = gridDim.x * blockDim.x;
    for (int i = tid; i < nX4; i += stride) {
        float4 v = X[i];
        ushort4 q;
        q.x = f32_to_bf16(v.x);
        q.y = f32_to_bf16(v.y);
        q.z = f32_to_bf16(v.z);
        q.w = f32_to_bf16(v.w);
        Xb[i] = q;
    }
    float s = 0.f;
    for (int i = tid; i < nW4; i += stride) {
        float4 v = W[i];
        s += fabsf(v.x) + fabsf(v.y) + fabsf(v.z) + fabsf(v.w);
    }
    double d = (double)s;
#pragma unroll
    for (int o = 32; o > 0; o >>= 1) d += __shfl_down(d, o, 64);
    __shared__ double lds[4];
    if ((threadIdx.x & 63) == 0) lds[threadIdx.x >> 6] = d;
    __syncthreads();
    if (threadIdx.x == 0)
        partials[blockIdx.x] = lds[0] + lds[1] + lds[2] + lds[3];
}

// ---------------- kernel 2: final reduce (2048 partials) + W-quantize ----------
__global__ void k2_quant(const float4* __restrict__ W, const double* __restrict__ partials,
                         double* __restrict__ sum_out, ushort4* __restrict__ Wq,
                         int nW4, double inv_cnt) {
    __shared__ double lds[4];
    double dsum;
    {
        int t = threadIdx.x;
        double d = 0.0;
#pragma unroll
        for (int i = 0; i < 8; ++i) d += partials[t + i * 256];
#pragma unroll
        for (int o = 32; o > 0; o >>= 1) d += __shfl_down(d, o, 64);
        if ((t & 63) == 0) lds[t >> 6] = d;
        __syncthreads();
        dsum = lds[0] + lds[1] + lds[2] + lds[3];
        if (blockIdx.x == 0 && t == 0) *sum_out = dsum;
    }
    float scale = (float)(dsum * inv_cnt);
    float d = scale + 1e-5f;
    int tid = blockIdx.x * blockDim.x + threadIdx.x;
    int stride = gridDim.x * blockDim.x;
    for (int i = tid; i < nW4; i += stride) {
        float4 v = W[i];
        ushort4 q;
        q.x = f32_to_bf16(rintf(v.x / d));   // IEEE divide + RNE == numpy round-half-even
        q.y = f32_to_bf16(rintf(v.y / d));
        q.z = f32_to_bf16(rintf(v.z / d));
        q.w = f32_to_bf16(rintf(v.w / d));
        Wq[i] = q;
    }
}

// ---------------- kernel 3: C[m,n] = scale * sum_k A[m,k]*B[n,k] ----------------
// 256x256 tile, BK=64, 8-phase schedule with counted vmcnt (round-1 best).
__global__ __launch_bounds__(512, 2) void gemm_bt(
    const unsigned short* __restrict__ A, const unsigned short* __restrict__ B,
    float* __restrict__ C, const double* __restrict__ sum, double inv_cnt) {

    // [buf][half][128*64] bf16 = 16 KiB per half; total 128 KiB
    __shared__ __attribute__((aligned(16))) unsigned short As[2][2][128 * 64];
    __shared__ __attribute__((aligned(16))) unsigned short Bs[2][2][128 * 64];

    const int tid  = threadIdx.x;
    const int w    = tid >> 6;     // wave 0..7
    const int lane = tid & 63;
    const int wm   = w >> 2;       // 0..1  -> C rows wm*128..+128
    const int wn   = w & 3;        // 0..3  -> C cols wn*64..+64

    // XCD-aware bijective swizzle: 512 blocks, 8 XCDs, 64 blocks each.
    const int bid = blockIdx.y * gridDim.x + blockIdx.x;
    const int swz = (bid & 7) * 64 + (bid >> 3);
    const size_t m0 = (size_t)(swz >> 4) * 256;
    const size_t n0 = (size_t)(swz & 15) * 256;

    // --- staging addressing -------------------------------------------------
    // One global_load_lds per wave = 64 lanes x 16 B = 8 rows x 128 B (linear
    // LDS dest).  lane -> row lane>>3, phys chunk lane&7.  The LDS image is
    // chunk-swizzled: phys chunk c holds global chunk c ^ (row&7), achieved by
    // pre-swizzling the per-lane GLOBAL source (dest stays linear, rule #21).
    const int srow   = lane >> 3;
    const int schunk = (lane & 7) ^ srow;
    const unsigned short* pA = A + (m0 + (size_t)(w * 8 + srow)) * K_DIM + schunk * 8;
    const unsigned short* pB = B + (n0 + (size_t)(w * 8 + srow)) * K_DIM + schunk * 8;

    // --- fragment read addressing (16x16x32 MFMA) ---------------------------
    // lane = (fm = lane&15, q = lane>>4); A frag: row = mf*16+fm, k = ks*32+q*8
    // logical chunk = ks*4+q; phys chunk = logical ^ (fm&7)  (row&7 == fm&7)
    const int fm    = lane & 15;
    const int q     = lane >> 4;
    const int cs0   = (q ^ (fm & 7)) * 8;          // ks=0, in shorts
    const int cs1   = ((4 + q) ^ (fm & 7)) * 8;    // ks=1
    const int abase = fm * 64;
    const int bh    = wn >> 1;                      // which B half this wave reads
    const int bbase = (wn & 1) * 4096 + fm * 64;    // row offset within the half

    floatx4 acc[8][4] = {};    // [m-frag][n-frag]
    bf16x8  afr[2][4];         // [ks][m-frag within current m-half]
    bf16x8  bfr[2][2][2];      // [n-half][ks][n-frag]

#define STAGE_A(bb, h, kt) do {                                                            \
        __builtin_amdgcn_global_load_lds(                                                  \
            (const __attribute__((address_space(1))) void*)(pA + ((h) * 128 + 0) * K_DIM + (kt) * 64), \
            (__attribute__((address_space(3))) void*)&As[bb][h][w * 512 + 0], 16, 0, 0);   \
        __builtin_amdgcn_global_load_lds(                                                  \
            (const __attribute__((address_space(1))) void*)(pA + ((h) * 128 + 64) * K_DIM + (kt) * 64), \
            (__attribute__((address_space(3))) void*)&As[bb][h][w * 512 + 4096], 16, 0, 0); \
    } while (0)

#define STAGE_B(bb, h, kt) do {                                                            \
        __builtin_amdgcn_global_load_lds(                                                  \
            (const __attribute__((address_space(1))) void*)(pB + ((h) * 128 + 0) * K_DIM + (kt) * 64), \
            (__attribute__((address_space(3))) void*)&Bs[bb][h][w * 512 + 0], 16, 0, 0);   \
        __builtin_amdgcn_global_load_lds(                                                  \
            (const __attribute__((address_space(1))) void*)(pB + ((h) * 128 + 64) * K_DIM + (kt) * 64), \
            (__attribute__((address_space(3))) void*)&Bs[bb][h][w * 512 + 4096], 16, 0, 0); \
    } while (0)

#define READ_A(b, mh) do {                                                                 \
        _Pragma("unroll")                                                                  \
        for (int t = 0; t < 4; ++t) {                                                      \
            afr[0][t] = *(const bf16x8*)&As[b][wm][((mh) * 4 + t) * 1024 + abase + cs0];   \
            afr[1][t] = *(const bf16x8*)&As[b][wm][((mh) * 4 + t) * 1024 + abase + cs1];   \
        }                                                                                  \
    } while (0)

#define READ_B(b, nh) do {                                                                 \
        _Pragma("unroll")                                                                  \
        for (int u = 0; u < 2; ++u) {                                                      \
            bfr[nh][0][u] = *(const bf16x8*)&Bs[b][bh][bbase + ((nh) * 2 + u) * 1024 + cs0]; \
            bfr[nh][1][u] = *(const bf16x8*)&Bs[b][bh][bbase + ((nh) * 2 + u) * 1024 + cs1]; \
        }                                                                                  \
    } while (0)

#define MFMA16(mh, nh) do {                                                                \
        _Pragma("unroll")                                                                  \
        for (int t = 0; t < 4; ++t)                                                        \
            _Pragma("unroll")                                                              \
            for (int u = 0; u < 2; ++u) {                                                  \
                acc[(mh) * 4 + t][(nh) * 2 + u] = __builtin_amdgcn_mfma_f32_16x16x32_bf16( \
                    afr[0][t], bfr[nh][0][u], acc[(mh) * 4 + t][(nh) * 2 + u], 0, 0, 0);   \
                acc[(mh) * 4 + t][(nh) * 2 + u] = __builtin_amdgcn_mfma_f32_16x16x32_bf16( \
                    afr[1][t], bfr[nh][1][u], acc[(mh) * 4 + t][(nh) * 2 + u], 0, 0, 0);   \
            }                                                                              \
    } while (0)

    // 4 phases per K-tile; quadrant order (mh,nh) = (0,0),(0,1),(1,0),(1,1).
    // ds_read counts per phase: 12, 4, 8, 0.  One counted vmcnt per K-tile.
#define KTILE(b, j, DOA, DOB, VMW) do {                                                    \
        /* phase 0 */                                                                      \
        READ_A(b, 0);                                                                      \
        READ_B(b, 0);                                                                      \
        if (DOA) STAGE_A((b) ^ 1, 0, (j) + 1);                                             \
        asm volatile("s_waitcnt lgkmcnt(8)" ::: "memory");                                 \
        __builtin_amdgcn_s_barrier();                                                      \
        asm volatile("s_waitcnt lgkmcnt(0)" ::: "memory");                                 \
        __builtin_amdgcn_s_setprio(1);                                                     \
        MFMA16(0, 0);                                                                      \
        __builtin_amdgcn_s_setprio(0);                                                     \
        __builtin_amdgcn_s_barrier();                                                      \
        /* phase 1 */                                                                      \
        READ_B(b, 1);                                                                      \
        if (DOA) STAGE_A((b) ^ 1, 1, (j) + 1);                                             \
        __builtin_amdgcn_s_barrier();                                                      \
        asm volatile("s_waitcnt lgkmcnt(0)" ::: "memory");                                 \
        __builtin_amdgcn_s_setprio(1);                                                     \
        MFMA16(0, 1);                                                                      \
        __builtin_amdgcn_s_setprio(0);                                                     \
        __builtin_amdgcn_s_barrier();                                                      \
        /* phase 2 */                                                                      \
        READ_A(b, 1);                                                                      \
        if (DOB) STAGE_B(b, 0, (j) + 2);                                                   \
        __builtin_amdgcn_s_barrier();                                                      \
        asm volatile("s_waitcnt lgkmcnt(0)" ::: "memory");                                 \
        __builtin_amdgcn_s_setprio(1);                                                     \
        MFMA16(1, 0);                                                                      \
        __builtin_amdgcn_s_setprio(0);                                                     \
        __builtin_amdgcn_s_barrier();                                                      \
        /* phase 3 */                                                                      \
        if (DOB) STAGE_B(b, 1, (j) + 2);                                                   \
        __builtin_amdgcn_s_barrier();                                                      \
        __builtin_amdgcn_s_setprio(1);                                                     \
        MFMA16(1, 1);                                                                      \
        __builtin_amdgcn_s_setprio(0);                                                     \
        asm volatile(VMW ::: "memory");                                                    \
        __builtin_amdgcn_s_barrier();                                                      \
    } while (0)

    // ---- prologue: kt0 (both A+B) -> buf0, B(kt1) -> buf1; force kt0 landed
    STAGE_B(0, 0, 0); STAGE_B(0, 1, 0);
    STAGE_A(0, 0, 0); STAGE_A(0, 1, 0);
    STAGE_B(1, 0, 1); STAGE_B(1, 1, 1);
    asm volatile("s_waitcnt vmcnt(4)" ::: "memory");
    __builtin_amdgcn_s_barrier();

    // ---- main loop: 2 K-tiles per iteration, compile-time buffer indices
    for (int j = 0; j < NKT - 2; j += 2) {
        KTILE(0, j,     1, 1, "s_waitcnt vmcnt(4)");
        KTILE(1, j + 1, 1, 1, "s_waitcnt vmcnt(4)");
    }
    // ---- epilogue: kt62 stages A(63), drains; kt63 stages nothing
    KTILE(0, NKT - 2, 1, 0, "s_waitcnt vmcnt(0)");
    KTILE(1, NKT - 1, 0, 0, "");

#undef KTILE
#undef MFMA16
#undef READ_B
#undef READ_A
#undef STAGE_B
#undef STAGE_A

    // ---- C write: C/D layout col = lane&15, row = (lane>>4)*4 + reg
    const float scale = (float)(*sum * inv_cnt);
    const size_t m0c = m0 + (size_t)wm * 128;
    const size_t n0c = n0 + (size_t)wn * 64;
#pragma unroll
    for (int mf = 0; mf < 8; ++mf) {
#pragma unroll
        for (int nf = 0; nf < 4; ++nf) {
            float* cp = C + (m0c + mf * 16 + q * 4) * N_DIM + n0c + nf * 16 + fm;
#pragma unroll
            for (int r = 0; r < 4; ++r)
                cp[(size_t)r * N_DIM] = acc[mf][nf][r] * scale;
        }
    }
}

extern "C" void kernel_launch(void* const* d_in, const int* in_sizes, int n_in,
                              void* d_out, int out_size, void* d_ws, size_t ws_size,
                              hipStream_t stream) {
    const float* x = (const float*)d_in[0];
    const float* W = (const float*)d_in[1];
    float* y = (float*)d_out;

    const int nW = in_sizes[1];            // 4096*4096
    const int M  = in_sizes[0] / K_DIM;    // 8192

    double* d_sum = (double*)d_ws;
    double* d_partials = (double*)((char*)d_ws + 16);                 // 2048 doubles
    unsigned short* xb = (unsigned short*)((char*)d_ws + 16 + 2048 * sizeof(double));
    unsigned short* wq = xb + (size_t)M * K_DIM;
    const double inv_cnt = 1.0 / (double)nW;

    k1_cast_reduce<<<2048, 256, 0, stream>>>((const float4*)x, (ushort4*)xb,
                                             (const float4*)W, d_partials,
                                             in_sizes[0] / 4, nW / 4);
    k2_quant<<<2048, 256, 0, stream>>>((const float4*)W, d_partials, d_sum,
                                       (ushort4*)wq, nW / 4, inv_cnt);

    dim3 grid(N_DIM / 256, M / 256);       // 16 x 32 = 512 blocks
    gemm_bt<<<grid, 512, 0, stream>>>(xb, wq, y, d_sum, inv_cnt);
}

// Round 9
// 559.754 us; speedup vs baseline: 1.0515x; 1.0200x over previous
//
#include <hip/hip_runtime.h>

// BitNet-style ternary matmul: y = (x @ round(W/mean|W|)^T) * mean|W|
// Round-9: GEMM phase-merge. The r1 skeleton (307 us, 38.5% MfmaUtil, thrice
// reproduced) spends ~2900 cyc/K-tile in barrier/phase-entry slack (8 wg-wide
// barriers per K-tile; LDS BW itself is only ~300 cyc, MFMA floor 2484).
// Change: 4 phases -> 2 phases per K-tile (8 -> 4 barriers), keeping the exact
// read -> bar -> lgkm(0) -> MFMA -> bar protection pattern and r1's registers.
//   p0: read A0(8)+B0(4)+B1(4) | stage A(j+1)h0+h1 | lgkm(8) | bar | lgkm(0) |
//       32 MFMA (mh=0, nh=0..1) | bar
//   p1: read A1(8)             | stage B(j+2)h0+h1 |           bar | lgkm(0) |
//       32 MFMA (mh=1, nh=0..1) | vm(4) | bar
// vm ledger: enter tile j with B(j+1)=4 outstanding; p0 +4 (A(j+1)) -> 8;
// p1 +4 (B(j+2)) -> 12; vm(4) drains B(j+1)+A(j+1), leaves B(j+2)=4.
// WAR: B(j+2) stage (p1) is after all B(j) reads (p0, barrier-drained);
// A(j+1) stage (p0) is after tile j-1's A reads (2 barriers upstream).
// Front-end kept as measured-neutral 2-kernel form (k1 cast+reduce, k2 quant);
// non-gemm time (~260 us) proved invariant to front-end structure (r1 vs r8).

#define K_DIM 4096
#define N_DIM 4096
#define NKT   64   // K_DIM / 64

typedef __bf16 bf16x8 __attribute__((ext_vector_type(8)));
typedef float floatx4 __attribute__((ext_vector_type(4)));

__device__ __forceinline__ unsigned short f32_to_bf16(float f) {
    unsigned int u = __float_as_uint(f);
    u += 0x7fffu + ((u >> 16) & 1u);   // round-to-nearest-even
    return (unsigned short)(u >> 16);
}

// ---------------- kernel 1: x -> bf16 cast  +  per-block partial sums of |W| ----
__global__ void k1_cast_reduce(const float4* __restrict__ X, ushort4* __restrict__ Xb,
                               const float4* __restrict__ W, double* __restrict__ partials,
                               int nX4, int nW4) {
    int tid = blockIdx.x * blockDim.x + threadIdx.x;
    int stride = gridDim.x * blockDim.x;
    for (int i = tid; i < nX4; i += stride) {
        float4 v = X[i];
        ushort4 q;
        q.x = f32_to_bf16(v.x);
        q.y = f32_to_bf16(v.y);
        q.z = f32_to_bf16(v.z);
        q.w = f32_to_bf16(v.w);
        Xb[i] = q;
    }
    float s = 0.f;
    for (int i = tid; i < nW4; i += stride) {
        float4 v = W[i];
        s += fabsf(v.x) + fabsf(v.y) + fabsf(v.z) + fabsf(v.w);
    }
    double d = (double)s;
#pragma unroll
    for (int o = 32; o > 0; o >>= 1) d += __shfl_down(d, o, 64);
    __shared__ double lds[4];
    if ((threadIdx.x & 63) == 0) lds[threadIdx.x >> 6] = d;
    __syncthreads();
    if (threadIdx.x == 0)
        partials[blockIdx.x] = lds[0] + lds[1] + lds[2] + lds[3];
}

// ---------------- kernel 2: final reduce (2048 partials) + W-quantize ----------
__global__ void k2_quant(const float4* __restrict__ W, const double* __restrict__ partials,
                         double* __restrict__ sum_out, ushort4* __restrict__ Wq,
                         int nW4, double inv_cnt) {
    __shared__ double lds[4];
    double dsum;
    {
        int t = threadIdx.x;
        double d = 0.0;
#pragma unroll
        for (int i = 0; i < 8; ++i) d += partials[t + i * 256];
#pragma unroll
        for (int o = 32; o > 0; o >>= 1) d += __shfl_down(d, o, 64);
        if ((t & 63) == 0) lds[t >> 6] = d;
        __syncthreads();
        dsum = lds[0] + lds[1] + lds[2] + lds[3];
        if (blockIdx.x == 0 && t == 0) *sum_out = dsum;
    }
    float scale = (float)(dsum * inv_cnt);
    float d = scale + 1e-5f;
    int tid = blockIdx.x * blockDim.x + threadIdx.x;
    int stride = gridDim.x * blockDim.x;
    for (int i = tid; i < nW4; i += stride) {
        float4 v = W[i];
        ushort4 q;
        q.x = f32_to_bf16(rintf(v.x / d));   // IEEE divide + RNE == numpy round-half-even
        q.y = f32_to_bf16(rintf(v.y / d));
        q.z = f32_to_bf16(rintf(v.z / d));
        q.w = f32_to_bf16(rintf(v.w / d));
        Wq[i] = q;
    }
}

// ---------------- kernel 3: C[m,n] = scale * sum_k A[m,k]*B[n,k] ----------------
// 256x256 tile, BK=64, 512 threads = 8 waves (2M x 4N), 128 KiB LDS.
__global__ __launch_bounds__(512, 2) void gemm_bt(
    const unsigned short* __restrict__ A, const unsigned short* __restrict__ B,
    float* __restrict__ C, const double* __restrict__ sum, double inv_cnt) {

    // [buf][half][128*64] bf16 = 16 KiB per half; total 128 KiB
    __shared__ __attribute__((aligned(16))) unsigned short As[2][2][128 * 64];
    __shared__ __attribute__((aligned(16))) unsigned short Bs[2][2][128 * 64];

    const int tid  = threadIdx.x;
    const int w    = tid >> 6;     // wave 0..7
    const int lane = tid & 63;
    const int wm   = w >> 2;       // 0..1  -> C rows wm*128..+128
    const int wn   = w & 3;        // 0..3  -> C cols wn*64..+64

    // XCD-aware bijective swizzle: 512 blocks, 8 XCDs, 64 blocks each.
    const int bid = blockIdx.y * gridDim.x + blockIdx.x;
    const int swz = (bid & 7) * 64 + (bid >> 3);
    const size_t m0 = (size_t)(swz >> 4) * 256;
    const size_t n0 = (size_t)(swz & 15) * 256;

    // --- staging addressing -------------------------------------------------
    // One global_load_lds per wave = 64 lanes x 16 B = 8 rows x 128 B (linear
    // LDS dest).  lane -> row lane>>3, phys chunk lane&7.  The LDS image is
    // chunk-swizzled: phys chunk c holds global chunk c ^ (row&7), achieved by
    // pre-swizzling the per-lane GLOBAL source (dest stays linear, rule #21).
    const int srow   = lane >> 3;
    const int schunk = (lane & 7) ^ srow;
    const unsigned short* pA = A + (m0 + (size_t)(w * 8 + srow)) * K_DIM + schunk * 8;
    const unsigned short* pB = B + (n0 + (size_t)(w * 8 + srow)) * K_DIM + schunk * 8;

    // --- fragment read addressing (16x16x32 MFMA) ---------------------------
    // lane = (fm = lane&15, q = lane>>4); A frag: row = mf*16+fm, k = ks*32+q*8
    // logical chunk = ks*4+q; phys chunk = logical ^ (fm&7)  (row&7 == fm&7)
    const int fm    = lane & 15;
    const int q     = lane >> 4;
    const int cs0   = (q ^ (fm & 7)) * 8;          // ks=0, in shorts
    const int cs1   = ((4 + q) ^ (fm & 7)) * 8;    // ks=1
    const int abase = fm * 64;
    const int bh    = wn >> 1;                      // which B half this wave reads
    const int bbase = (wn & 1) * 4096 + fm * 64;    // row offset within the half

    floatx4 acc[8][4] = {};    // [m-frag][n-frag]
    bf16x8  afr[2][4];         // [ks][m-frag within current m-half]
    bf16x8  bfr[2][2][2];      // [n-half][ks][n-frag]

#define STAGE_A(bb, h, kt) do {                                                            \
        __builtin_amdgcn_global_load_lds(                                                  \
            (const __attribute__((address_space(1))) void*)(pA + ((h) * 128 + 0) * K_DIM + (kt) * 64), \
            (__attribute__((address_space(3))) void*)&As[bb][h][w * 512 + 0], 16, 0, 0);   \
        __builtin_amdgcn_global_load_lds(                                                  \
            (const __attribute__((address_space(1))) void*)(pA + ((h) * 128 + 64) * K_DIM + (kt) * 64), \
            (__attribute__((address_space(3))) void*)&As[bb][h][w * 512 + 4096], 16, 0, 0); \
    } while (0)

#define STAGE_B(bb, h, kt) do {                                                            \
        __builtin_amdgcn_global_load_lds(                                                  \
            (const __attribute__((address_space(1))) void*)(pB + ((h) * 128 + 0) * K_DIM + (kt) * 64), \
            (__attribute__((address_space(3))) void*)&Bs[bb][h][w * 512 + 0], 16, 0, 0);   \
        __builtin_amdgcn_global_load_lds(                                                  \
            (const __attribute__((address_space(1))) void*)(pB + ((h) * 128 + 64) * K_DIM + (kt) * 64), \
            (__attribute__((address_space(3))) void*)&Bs[bb][h][w * 512 + 4096], 16, 0, 0); \
    } while (0)

#define READ_A(b, mh) do {                                                                 \
        _Pragma("unroll")                                                                  \
        for (int t = 0; t < 4; ++t) {                                                      \
            afr[0][t] = *(const bf16x8*)&As[b][wm][((mh) * 4 + t) * 1024 + abase + cs0];   \
            afr[1][t] = *(const bf16x8*)&As[b][wm][((mh) * 4 + t) * 1024 + abase + cs1];   \
        }                                                                                  \
    } while (0)

#define READ_B(b, nh) do {                                                                 \
        _Pragma("unroll")                                                                  \
        for (int u = 0; u < 2; ++u) {                                                      \
            bfr[nh][0][u] = *(const bf16x8*)&Bs[b][bh][bbase + ((nh) * 2 + u) * 1024 + cs0]; \
            bfr[nh][1][u] = *(const bf16x8*)&Bs[b][bh][bbase + ((nh) * 2 + u) * 1024 + cs1]; \
        }                                                                                  \
    } while (0)

#define MFMA16(mh, nh) do {                                                                \
        _Pragma("unroll")                                                                  \
        for (int t = 0; t < 4; ++t)                                                        \
            _Pragma("unroll")                                                              \
            for (int u = 0; u < 2; ++u) {                                                  \
                acc[(mh) * 4 + t][(nh) * 2 + u] = __builtin_amdgcn_mfma_f32_16x16x32_bf16( \
                    afr[0][t], bfr[nh][0][u], acc[(mh) * 4 + t][(nh) * 2 + u], 0, 0, 0);   \
                acc[(mh) * 4 + t][(nh) * 2 + u] = __builtin_amdgcn_mfma_f32_16x16x32_bf16( \
                    afr[1][t], bfr[nh][1][u], acc[(mh) * 4 + t][(nh) * 2 + u], 0, 0, 0);   \
            }                                                                              \
    } while (0)

    // 2 phases per K-tile (4 barriers).  One counted vm(4) per K-tile.
#define KTILE(b, j, DOA, DOB, VMW) do {                                                    \
        /* phase 0: all B reads + A-half 0; stage A(j+1) both halves */                    \
        READ_A(b, 0);                                                                      \
        READ_B(b, 0);                                                                      \
        READ_B(b, 1);                                                                      \
        if (DOA) { STAGE_A((b) ^ 1, 0, (j) + 1); STAGE_A((b) ^ 1, 1, (j) + 1); }           \
        asm volatile("s_waitcnt lgkmcnt(8)" ::: "memory");                                 \
        __builtin_amdgcn_s_barrier();                                                      \
        asm volatile("s_waitcnt lgkmcnt(0)" ::: "memory");                                 \
        __builtin_amdgcn_s_setprio(1);                                                     \
        MFMA16(0, 0);                                                                      \
        MFMA16(0, 1);                                                                      \
        __builtin_amdgcn_s_setprio(0);                                                     \
        __builtin_amdgcn_s_barrier();                                                      \
        /* phase 1: A-half 1; stage B(j+2) both halves (B(j) fully read in p0) */          \
        READ_A(b, 1);                                                                      \
        if (DOB) { STAGE_B(b, 0, (j) + 2); STAGE_B(b, 1, (j) + 2); }                       \
        __builtin_amdgcn_s_barrier();                                                      \
        asm volatile("s_waitcnt lgkmcnt(0)" ::: "memory");                                 \
        __builtin_amdgcn_s_setprio(1);                                                     \
        MFMA16(1, 0);                                                                      \
        MFMA16(1, 1);                                                                      \
        __builtin_amdgcn_s_setprio(0);                                                     \
        asm volatile(VMW ::: "memory");                                                    \
        __builtin_amdgcn_s_barrier();                                                      \
    } while (0)

    // ---- prologue: kt0 (both A+B) -> buf0, B(kt1) -> buf1; force kt0 landed
    STAGE_B(0, 0, 0); STAGE_B(0, 1, 0);
    STAGE_A(0, 0, 0); STAGE_A(0, 1, 0);
    STAGE_B(1, 0, 1); STAGE_B(1, 1, 1);
    asm volatile("s_waitcnt vmcnt(4)" ::: "memory");
    __builtin_amdgcn_s_barrier();

    // ---- main loop: 2 K-tiles per iteration, compile-time buffer indices
    for (int j = 0; j < NKT - 2; j += 2) {
        KTILE(0, j,     1, 1, "s_waitcnt vmcnt(4)");
        KTILE(1, j + 1, 1, 1, "s_waitcnt vmcnt(4)");
    }
    // ---- epilogue: kt62 stages A(63), drains; kt63 stages nothing
    KTILE(0, NKT - 2, 1, 0, "s_waitcnt vmcnt(0)");
    KTILE(1, NKT - 1, 0, 0, "");

#undef KTILE
#undef MFMA16
#undef READ_B
#undef READ_A
#undef STAGE_B
#undef STAGE_A

    // ---- C write: C/D layout col = lane&15, row = (lane>>4)*4 + reg
    const float scale = (float)(*sum * inv_cnt);
    const size_t m0c = m0 + (size_t)wm * 128;
    const size_t n0c = n0 + (size_t)wn * 64;
#pragma unroll
    for (int mf = 0; mf < 8; ++mf) {
#pragma unroll
        for (int nf = 0; nf < 4; ++nf) {
            float* cp = C + (m0c + mf * 16 + q * 4) * N_DIM + n0c + nf * 16 + fm;
#pragma unroll
            for (int r = 0; r < 4; ++r)
                cp[(size_t)r * N_DIM] = acc[mf][nf][r] * scale;
        }
    }
}

extern "C" void kernel_launch(void* const* d_in, const int* in_sizes, int n_in,
                              void* d_out, int out_size, void* d_ws, size_t ws_size,
                              hipStream_t stream) {
    const float* x = (const float*)d_in[0];
    const float* W = (const float*)d_in[1];
    float* y = (float*)d_out;

    const int nW = in_sizes[1];            // 4096*4096
    const int M  = in_sizes[0] / K_DIM;    // 8192

    double* d_sum = (double*)d_ws;
    double* d_partials = (double*)((char*)d_ws + 16);                 // 2048 doubles
    unsigned short* xb = (unsigned short*)((char*)d_ws + 16 + 2048 * sizeof(double));
    unsigned short* wq = xb + (size_t)M * K_DIM;
    const double inv_cnt = 1.0 / (double)nW;

    k1_cast_reduce<<<2048, 256, 0, stream>>>((const float4*)x, (ushort4*)xb,
                                             (const float4*)W, d_partials,
                                             in_sizes[0] / 4, nW / 4);
    k2_quant<<<2048, 256, 0, stream>>>((const float4*)W, d_partials, d_sum,
                                       (ushort4*)wq, nW / 4, inv_cnt);

    dim3 grid(N_DIM / 256, M / 256);       // 16 x 32 = 512 blocks
    gemm_bt<<<grid, 512, 0, stream>>>(xb, wq, y, d_sum, inv_cnt);
}